// Round 4
// baseline (609.391 us; speedup 1.0000x reference)
//
#include <hip/hip_runtime.h>
#include <hip/hip_bf16.h>

#define ALPHA   0.3f
#define NEG_INF (-9e15f)
#define BN_EPS  1e-5f

typedef _Float16 f16x4 __attribute__((ext_vector_type(4)));
typedef _Float16 f16x8 __attribute__((ext_vector_type(8)));
typedef float    f32x4 __attribute__((ext_vector_type(4)));
typedef unsigned u32x4 __attribute__((ext_vector_type(4)));
typedef unsigned long long u64;

// ---------------------------------------------------------------------------
// K0 (R7: wcat merged into pack -- one fewer launch):
//  blocks < 768 also pack Wh[8,768,32] f32 -> WcatT[256][768] f16 (B^T layout).
//  all 12800 blocks pack adj>0 bitmasks: Mw[row][4] u64 (41MB -> 1.6MB,
//  L2-resident; aliases Y region, live only until k_attn1 -- R6 footprint).
// ---------------------------------------------------------------------------
__global__ __launch_bounds__(256) void k_pack(const int* __restrict__ adj,
                                              u64* __restrict__ Mw,
                                              const float* __restrict__ Wh,
                                              _Float16* __restrict__ WT)
{
    if (blockIdx.x < 768) {
        const int o = blockIdx.x * 256 + threadIdx.x;   // < 196608
        const int n = o / 768, k = o - n * 768;
        WT[o] = (_Float16)Wh[((n >> 5) * 768 + k) * 32 + (n & 31)];
    }
    const int w = threadIdx.x >> 6, lane = threadIdx.x & 63;
    const int row = blockIdx.x * 4 + w;             // < 51200
    const int* ar = adj + (size_t)row * 200;
    #pragma unroll
    for (int t = 0; t < 4; ++t) {
        const int j = t * 64 + lane;
        const int a = ar[j < 200 ? j : 199];
        const u64 bal = __ballot(j < 200 && a > 0);
        if (lane == 0) Mw[(size_t)row * 4 + t] = bal;
    }
}

// ---------------------------------------------------------------------------
// K1: H[51200,256] = feat @ Wcat via f16 MFMA.
// R4: f32-VALU version was compute-bound (285us, VALUBusy=67%, MfmaUtil=0).
// Tile 64Mx256N, BK=64, 4 waves (each 64x64 = 4x4 16x16 tiles). feat converted
// f32->f16 inline into Af (rows padded 64->72 f16). M-only grid: feat read once.
// ---------------------------------------------------------------------------
__global__ __launch_bounds__(256) void k_gemm1(const float* __restrict__ A,
                                               const _Float16* __restrict__ WT,
                                               float* __restrict__ H)
{
    __shared__ _Float16 Af[64][72];    // [m][k]
    __shared__ _Float16 Bf[256][72];   // [n][k]
    const int tid  = threadIdx.x;
    const int wv   = tid >> 6;
    const int lane = tid & 63;
    const int r16  = lane & 15, q = lane >> 4;
    const size_t m_blk = (size_t)blockIdx.x * 64;
    const int wn = wv * 64;
    const int arow = tid >> 2, akb = (tid & 3) * 16;
    f32x4 acc[4][4] = {};   // [mi][ni]

    for (int kt = 0; kt < 768; kt += 64) {
        __syncthreads();
        #pragma unroll
        for (int p = 0; p < 4; ++p) {   // A: 64 rows x 64 k, f32 -> f16
            const float4 a4 = *(const float4*)&A[(m_blk + arow) * 768 + kt + akb + p * 4];
            f16x4 h4 = { (_Float16)a4.x, (_Float16)a4.y, (_Float16)a4.z, (_Float16)a4.w };
            *(f16x4*)&Af[arow][akb + p * 4] = h4;
        }
        #pragma unroll
        for (int p = 0; p < 8; ++p) {   // B: row n = tid, k 0..63 (f16 in global)
            f16x8 w8 = *(const f16x8*)&WT[tid * 768 + kt + p * 8];
            *(f16x8*)&Bf[tid][p * 8] = w8;
        }
        __syncthreads();
        #pragma unroll
        for (int kc = 0; kc < 64; kc += 32) {
            f16x8 af[4], bf[4];
            #pragma unroll
            for (int i = 0; i < 4; ++i)
                af[i] = *(const f16x8*)&Af[i * 16 + r16][kc + q * 8];
            #pragma unroll
            for (int j = 0; j < 4; ++j)
                bf[j] = *(const f16x8*)&Bf[wn + j * 16 + r16][kc + q * 8];
            #pragma unroll
            for (int i = 0; i < 4; ++i)
                #pragma unroll
                for (int j = 0; j < 4; ++j)
                    acc[i][j] = __builtin_amdgcn_mfma_f32_16x16x32_f16(
                        af[i], bf[j], acc[i][j], 0, 0, 0);
        }
    }
    #pragma unroll
    for (int i = 0; i < 4; ++i)
        #pragma unroll
        for (int j = 0; j < 4; ++j)
            #pragma unroll
            for (int r = 0; r < 4; ++r) {
                const int m = i * 16 + q * 4 + r;       // D row
                const int n = wn + j * 16 + r16;        // D col
                H[(m_blk + m) * 256 + n] = acc[i][j][r];
            }
}

// ---------------------------------------------------------------------------
// K2 (R8): per (b, head) masked softmax + att@H + elu + BN.
// R7 post-mortem: R6 (131us) and R7 (170us) both run ~3.6 TB/s aggregate --
// the kernel is TRAFFIC-bound; R7's 512-thread restructure ADDED write traffic
// (190->330MB). R8 reverts to the proven 256-thread/4-wave schedule and cuts
// bytes instead:
//  (a) fused stage+score pass: ONE float4 sweep over f32 H produces both the
//      f16 HsT (B^T) and s1/s2 (8-lane shfl-tree dot, f32 math -- R3 lesson).
//      Kills the second 25.6KB/block H read and one barrier.
//  (b) XCD grouping: b = blockIdx&255, head = blockIdx>>8. Round-robin
//      dispatch then puts all 8 heads of batch b on ONE XCD: the 8x mask
//      re-read collapses to one L2 fetch, and the heads' interleaved 128B
//      sectors of the same H rows (read+write) merge in one L2 instead of
//      thrashing partial lines across 8 XCDs.
// Main loop unchanged from R6: wave owns 16-row m-tile, P in MFMA A-fragment
// registers, masked max, HsT stride 232 (conflict-free), 13 tiles/4 waves.
// ---------------------------------------------------------------------------
__global__ __launch_bounds__(256, 6) void k_attn1(float* __restrict__ H,
    const unsigned* __restrict__ Mw, const float* __restrict__ ah,
    const float* __restrict__ bng, const float* __restrict__ bnb,
    const float* __restrict__ bnm, const float* __restrict__ bnv)
{
    __shared__ alignas(16) _Float16 HsT[32][232];   // [f][j] B^T, stride 464B
    __shared__ alignas(16) unsigned Ml[208][8];     // row bitmask
    __shared__ alignas(16) float s2[224];
    __shared__ alignas(16) float s1[208];
    __shared__ float bnA[208], bnB[208];
    const int tid  = threadIdx.x;
    const int b    = blockIdx.x & 255;              // same b -> same XCD
    const int head = blockIdx.x >> 8;
    float* Hb = H + (size_t)b * 200 * 256 + head * 32;
    const unsigned* Mb = Mw + (size_t)b * 200 * 8;

    // ---- fused stage + s1/s2: one pass over f32 H ----
    const int fq = tid & 7;          // lane's f-quad (f = fq*4 .. fq*4+3)
    const int gn = tid >> 3;         // row-group base (8 lanes per row)
    const float4 a1 = *(const float4*)&ah[head * 64 + fq * 4];
    const float4 a2 = *(const float4*)&ah[head * 64 + 32 + fq * 4];
    #pragma unroll
    for (int it = 0; it < 7; ++it) {
        const int n = gn + 32 * it;
        if (n < 200) {
            const float4 h4 = *(const float4*)&Hb[n * 256 + fq * 4];
            HsT[fq * 4 + 0][n] = (_Float16)h4.x;
            HsT[fq * 4 + 1][n] = (_Float16)h4.y;
            HsT[fq * 4 + 2][n] = (_Float16)h4.z;
            HsT[fq * 4 + 3][n] = (_Float16)h4.w;
            float v1 = h4.x * a1.x + h4.y * a1.y + h4.z * a1.z + h4.w * a1.w;
            float v2 = h4.x * a2.x + h4.y * a2.y + h4.z * a2.z + h4.w * a2.w;
            v1 += __shfl_xor(v1, 1); v2 += __shfl_xor(v2, 1);
            v1 += __shfl_xor(v1, 2); v2 += __shfl_xor(v2, 2);
            v1 += __shfl_xor(v1, 4); v2 += __shfl_xor(v2, 4);
            if (fq == 0) { s1[n] = v1; s2[n] = v2; }
        }
    }
    // K-pads of HsT (cols 200..231)
    for (int idx = tid; idx < 32 * 32; idx += 256) {
        int f = idx >> 5, c = 200 + (idx & 31);
        HsT[f][c] = (_Float16)0.f;
    }
    // masks as uint4 (208 rows x 2 uint4)
    for (int idx = tid; idx < 416; idx += 256) {
        const int rr = idx >> 1, hf = idx & 1;
        u32x4 mv = {0u, 0u, 0u, 0u};
        if (rr < 200) mv = *(const u32x4*)&Mb[rr * 8 + hf * 4];
        *(u32x4*)&Ml[rr][hf * 4] = mv;
    }
    // s1/s2 pads + fused BN coeffs
    if (tid < 8) s1[200 + tid] = 0.f;
    if (tid >= 8 && tid < 32) s2[200 + (tid - 8)] = 0.f;
    if (tid < 200) {
        const float iv = bng[tid] * rsqrtf(bnv[tid] + BN_EPS);
        bnA[tid] = iv; bnB[tid] = bnb[tid] - bnm[tid] * iv;
    }
    __syncthreads();

    const int lane = tid & 63, wv = tid >> 6;      // wv 0..3
    const int r16 = lane & 15, q = lane >> 4;

    for (int tile = wv; tile < 13; tile += 4) {
        const int m0  = tile * 16;
        const int row = m0 + r16;                  // this lane's P-row
        const float s1i = s1[row];
        const u32x4 mwa = *(const u32x4*)&Ml[row][0];
        const u32x4 mwb = *(const u32x4*)&Ml[row][4];
        const unsigned mw[7] = {mwa[0], mwa[1], mwa[2], mwa[3],
                                mwb[0], mwb[1], mwb[2]};

        // pass 1: masked row max
        float m = -INFINITY;
        #pragma unroll
        for (int ks = 0; ks < 7; ++ks) {
            const f32x4 sA = *(const f32x4*)&s2[ks * 32 + q * 8];
            const f32x4 sB = *(const f32x4*)&s2[ks * 32 + q * 8 + 4];
            const unsigned wb = mw[ks] >> (q * 8);
            #pragma unroll
            for (int e = 0; e < 8; ++e) {
                const float sv = (e < 4) ? sA[e] : sB[e - 4];
                const float t = s1i + sv;
                const float tl = fmaxf(t, ALPHA * t);   // leaky via max (a<1)
                m = fmaxf(m, ((wb >> e) & 1u) ? tl : -INFINITY);
            }
        }
        m = fmaxf(m, __shfl_xor(m, 16));
        m = fmaxf(m, __shfl_xor(m, 32));

        // pass 2: p = mask ? exp(e-m) : 0, packed straight into A-fragments
        float s = 0.f;
        f16x8 pa[7];
        #pragma unroll
        for (int ks = 0; ks < 7; ++ks) {
            const f32x4 sA = *(const f32x4*)&s2[ks * 32 + q * 8];
            const f32x4 sB = *(const f32x4*)&s2[ks * 32 + q * 8 + 4];
            const unsigned wb = mw[ks] >> (q * 8);
            #pragma unroll
            for (int e = 0; e < 8; ++e) {
                const float sv = (e < 4) ? sA[e] : sB[e - 4];
                float t = s1i + sv;
                t = fmaxf(t, ALPHA * t);
                float pe = __expf(t - m);            // <= 1: f16-safe
                pe = ((wb >> e) & 1u) ? pe : 0.f;
                s += pe;
                pa[ks][e] = (_Float16)pe;
            }
        }
        s += __shfl_xor(s, 16);
        s += __shfl_xor(s, 32);
        const float sinv = 1.f / s;

        // O[16,32] = P @ H : 2 f-tiles, A from registers, B from padded HsT
        f32x4 acc0 = {0.f, 0.f, 0.f, 0.f}, acc1 = {0.f, 0.f, 0.f, 0.f};
        #pragma unroll
        for (int ks = 0; ks < 7; ++ks) {
            const int k0 = ks * 32 + q * 8;
            const f16x8 b0 = *(const f16x8*)&HsT[r16][k0];
            const f16x8 b1 = *(const f16x8*)&HsT[16 + r16][k0];
            acc0 = __builtin_amdgcn_mfma_f32_16x16x32_f16(pa[ks], b0, acc0, 0, 0, 0);
            acc1 = __builtin_amdgcn_mfma_f32_16x16x32_f16(pa[ks], b1, acc1, 0, 0, 0);
        }
        // D layout: row = q*4+r, col = r16. sinv for row i lives at lane i&15.
        float rv[4];
        #pragma unroll
        for (int r = 0; r < 4; ++r) rv[r] = __shfl(sinv, q * 4 + r);
        #pragma unroll
        for (int r = 0; r < 4; ++r) {
            const int i = m0 + q * 4 + r;
            if (i < 200) {
                float o0 = acc0[r] * rv[r];
                float o1 = acc1[r] * rv[r];
                o0 = o0 > 0.f ? o0 : expm1f(o0);     // elu
                o1 = o1 > 0.f ? o1 : expm1f(o1);
                const float ga = bnA[i], gb = bnB[i];
                Hb[i * 256 + r16]      = o0 * ga + gb;
                Hb[i * 256 + 16 + r16] = o1 * ga + gb;
            }
        }
    }
}

// ---------------------------------------------------------------------------
// K3: Y[51200,36] = x[51200,256] @ [W_sent | W_para | W_qt]
// Col group g (9 cols) lives at 16B-aligned 12-float slot in LDS; inner loop
// kept at unroll-4 to stop LLVM from fully unrolling and spilling (round-1
// pathology: VGPR=256, 1.9 GB scratch traffic, 1530 us).
// ---------------------------------------------------------------------------
__global__ __launch_bounds__(256) void k_gemm2(const float* __restrict__ X,
    const float* __restrict__ Ws, const float* __restrict__ Wp,
    const float* __restrict__ Wq, float* __restrict__ Y)
{
    __shared__ float Wl[256][48];   // [k][12*g + c], c<9 used, pads never read
    __shared__ float XsT[64][68];   // [k][row]
    const int tid = threadIdx.x;
    {   // stage weights (once): thread tid = row k
        const int k = tid;
        #pragma unroll
        for (int c = 0; c < 36; ++c) {
            float v;
            if      (c == 0) v = Ws[k * 2 + 0];
            else if (c == 1) v = Ws[k * 2 + 1];
            else if (c == 2) v = Wp[k * 2 + 0];
            else if (c == 3) v = Wp[k * 2 + 1];
            else             v = Wq[k * 32 + (c - 4)];
            Wl[k][12 * (c / 9) + (c % 9)] = v;
        }
    }
    const int r  = tid & 63;        // row within tile (wave-contiguous)
    const int cg = tid >> 6;        // col group 0..3 (uniform per wave)
    const size_t row0 = (size_t)blockIdx.x * 64;
    float acc[9] = {};

    for (int kt = 0; kt < 256; kt += 64) {
        __syncthreads();
        #pragma unroll
        for (int i = 0; i < 4; ++i) {      // 64x64 X tile, transposed into LDS
            int l = tid + 256 * i;
            int row = l >> 4;
            int k4 = (l & 15) * 4;
            const float4 x4 = *(const float4*)&X[(row0 + row) * 256 + kt + k4];
            XsT[k4 + 0][row] = x4.x; XsT[k4 + 1][row] = x4.y;
            XsT[k4 + 2][row] = x4.z; XsT[k4 + 3][row] = x4.w;
        }
        __syncthreads();
        #pragma unroll 4
        for (int k = 0; k < 64; ++k) {
            const float xv = XsT[k][r];
            const float4 w0 = *(const float4*)&Wl[kt + k][12 * cg + 0];
            const float4 w1 = *(const float4*)&Wl[kt + k][12 * cg + 4];
            const float  w2 = Wl[kt + k][12 * cg + 8];
            acc[0] += xv * w0.x; acc[1] += xv * w0.y;
            acc[2] += xv * w0.z; acc[3] += xv * w0.w;
            acc[4] += xv * w1.x; acc[5] += xv * w1.y;
            acc[6] += xv * w1.z; acc[7] += xv * w1.w;
            acc[8] += xv * w2;
        }
    }
    float* yr = Y + (row0 + r) * 36 + cg * 9;
    #pragma unroll
    for (int c = 0; c < 9; ++c) yr[c] = acc[c];
}

// ---------------------------------------------------------------------------
// K4 (R7): 2nd-layer attention, 512 threads: stage 14 iters, row loop 8 waves.
// Direct adj loads (Mw is dead -- overwritten by k_gemm2).
// ---------------------------------------------------------------------------
__global__ __launch_bounds__(512, 4) void k_attn2(const float* __restrict__ Y,
    const int* __restrict__ adj, const float* __restrict__ a_s,
    const float* __restrict__ a_p, const float* __restrict__ a_q,
    const float* __restrict__ W2, float* __restrict__ out)
{
    __shared__ float Ys[200][37];
    __shared__ float s1s[200], s2s[200], p1s[200], p2s[200], sq2[200];
    __shared__ float p0[200];
    __shared__ float hqt[32];
    __shared__ float sumq_s;
    __shared__ float asl[4], apl[4], aql[64], w2l[64];
    const int tid  = threadIdx.x;
    const int b    = blockIdx.x >> 1;
    const int half = blockIdx.x & 1;
    const float* Yb = Y + (size_t)b * 7200;
    const int* adjb = adj + (size_t)b * 200 * 200;

    for (int idx = tid; idx < 7200; idx += 512) {
        int j = idx / 36;
        int c = idx - j * 36;
        Ys[j][c] = Yb[idx];
    }
    if (tid < 4)  { asl[tid] = a_s[tid]; apl[tid] = a_p[tid]; }
    if (tid >= 64 && tid < 128) { aql[tid - 64] = a_q[tid - 64]; w2l[tid - 64] = W2[tid - 64]; }
    __syncthreads();

    if (tid < 200) {
        int j = tid;
        s1s[j] = Ys[j][0] * asl[0] + Ys[j][1] * asl[1];
        s2s[j] = Ys[j][0] * asl[2] + Ys[j][1] * asl[3];
        p1s[j] = Ys[j][2] * apl[0] + Ys[j][3] * apl[1];
        p2s[j] = Ys[j][2] * apl[2] + Ys[j][3] * apl[3];
        float a = 0.f;
        #pragma unroll
        for (int f = 0; f < 32; ++f) a += Ys[j][4 + f] * aql[32 + f];
        sq2[j] = a;
    }
    __syncthreads();

    const int w = tid >> 6, lane = tid & 63;       // w 0..7
    for (int ii = w; ii < 100; ii += 8) {   // one wave per row
        const int i = half * 100 + ii;
        const float s1i = s1s[i], p1i = p1s[i];
        float ms = -INFINITY, mp = -INFINITY;
        float es[4], ep[4];
        #pragma unroll
        for (int t = 0; t < 4; ++t) {
            int j = lane + 64 * t;
            int jj = j < 200 ? j : 0;
            int a = (j < 200) ? adjb[i * 200 + j] : 0;
            float e1 = s1i + s2s[jj]; e1 = e1 >= 0.f ? e1 : ALPHA * e1;
            float e2 = p1i + p2s[jj]; e2 = e2 >= 0.f ? e2 : ALPHA * e2;
            es[t] = (a > 0) ? e1 : (j < 200 ? NEG_INF : -INFINITY);
            ep[t] = (a > 0) ? e2 : (j < 200 ? NEG_INF : -INFINITY);
            ms = fmaxf(ms, es[t]); mp = fmaxf(mp, ep[t]);
        }
        #pragma unroll
        for (int off = 32; off >= 1; off >>= 1) {
            ms = fmaxf(ms, __shfl_xor(ms, off));
            mp = fmaxf(mp, __shfl_xor(mp, off));
        }
        float ss = 0.f, sp = 0.f, os0 = 0.f, os1 = 0.f, op0 = 0.f, op1 = 0.f;
        #pragma unroll
        for (int t = 0; t < 4; ++t) {
            int j = lane + 64 * t;
            int jj = j < 200 ? j : 0;
            float pes = __expf(es[t] - ms);
            float pep = __expf(ep[t] - mp);
            ss += pes; sp += pep;
            os0 += pes * Ys[jj][0]; os1 += pes * Ys[jj][1];
            op0 += pep * Ys[jj][2]; op1 += pep * Ys[jj][3];
        }
        #pragma unroll
        for (int off = 32; off >= 1; off >>= 1) {
            ss  += __shfl_xor(ss, off);  sp  += __shfl_xor(sp, off);
            os0 += __shfl_xor(os0, off); os1 += __shfl_xor(os1, off);
            op0 += __shfl_xor(op0, off); op1 += __shfl_xor(op1, off);
        }
        if (lane == 0) {
            float v0 = os0 / ss, v1 = os1 / ss;
            out[((size_t)b * 200 + i) * 2 + 0] = 1.f / (1.f + __expf(-v0));
            out[((size_t)b * 200 + i) * 2 + 1] = 1.f / (1.f + __expf(-v1));
            float q0 = op0 / sp, q1 = op1 / sp;
            out[102400 + ((size_t)b * 200 + i) * 2 + 0] = q0 > 0.f ? q0 : expm1f(q0);
            out[102400 + ((size_t)b * 200 + i) * 2 + 1] = q1 > 0.f ? q1 : expm1f(q1);
        }
    }

    // ---- qtype head: attention row 0 only (half 0 blocks) ----
    if (half == 0 && tid < 64) {
        float s1q = 0.f;
        #pragma unroll
        for (int f = 0; f < 32; ++f) s1q += Ys[0][4 + f] * aql[f];
        float mq = -INFINITY;
        float eq[4];
        #pragma unroll
        for (int t = 0; t < 4; ++t) {
            int j = tid + 64 * t;
            int jj = j < 200 ? j : 0;
            int a = (j < 200) ? adjb[j] : 0;
            float e = s1q + sq2[jj]; e = e >= 0.f ? e : ALPHA * e;
            eq[t] = (a > 0) ? e : (j < 200 ? NEG_INF : -INFINITY);
            mq = fmaxf(mq, eq[t]);
        }
        #pragma unroll
        for (int off = 32; off >= 1; off >>= 1) mq = fmaxf(mq, __shfl_xor(mq, off));
        float sq = 0.f;
        #pragma unroll
        for (int t = 0; t < 4; ++t) {
            int j = tid + 64 * t;
            float pe = __expf(eq[t] - mq);
            sq += pe;
            if (j < 200) p0[j] = pe;
        }
        #pragma unroll
        for (int off = 32; off >= 1; off >>= 1) sq += __shfl_xor(sq, off);
        if (tid == 0) sumq_s = sq;
    }
    __syncthreads();
    if (half == 0 && tid < 32) {
        float acc = 0.f;
        for (int j = 0; j < 200; ++j) acc += p0[j] * Ys[j][4 + tid];
        hqt[tid] = acc / sumq_s;
    }
    __syncthreads();
    if (half == 0 && tid < 2) {
        float v = 0.f;
        #pragma unroll
        for (int f = 0; f < 32; ++f) v += hqt[f] * w2l[f * 2 + tid];
        out[204800 + (size_t)b * 2 + tid] = v > 0.f ? v : expm1f(v);
    }
}

// ---------------------------------------------------------------------------
extern "C" void kernel_launch(void* const* d_in, const int* in_sizes, int n_in,
                              void* d_out, int out_size, void* d_ws, size_t ws_size,
                              hipStream_t stream) {
    const float* feat   = (const float*)d_in[0];   // [256,200,768]
    const int*   adj    = (const int*)  d_in[1];   // [256,200,200]
    const float* Wh     = (const float*)d_in[2];   // [8,768,32]
    const float* ah     = (const float*)d_in[3];   // [8,64,1]
    const float* W_sent = (const float*)d_in[4];   // [256,2]
    const float* a_sent = (const float*)d_in[5];   // [4,1]
    const float* W_para = (const float*)d_in[6];   // [256,2]
    const float* a_para = (const float*)d_in[7];   // [4,1]
    const float* W_qt   = (const float*)d_in[8];   // [256,32]
    const float* a_qt   = (const float*)d_in[9];   // [64,1]
    const float* W2     = (const float*)d_in[10];  // [32,2]
    const float* bng    = (const float*)d_in[11];
    const float* bnb    = (const float*)d_in[12];
    const float* bnm    = (const float*)d_in[13];
    const float* bnv    = (const float*)d_in[14];

    float* H = (float*)d_ws;                 // [51200,256] -> becomes x in place
    float* Y = H + (size_t)51200 * 256;      // [51200,36]
    _Float16* WT = (_Float16*)(Y + (size_t)51200 * 36);  // [256,768] f16
    // Mw [51200][4] u64 = 1.6MB ALIASES Y (live only between k_pack and
    // k_attn1; k_gemm2 overwrites it afterwards). Footprint unchanged.
    u64* Mw = (u64*)Y;
    float* out = (float*)d_out;

    k_pack<<<12800, 256, 0, stream>>>(adj, Mw, Wh, WT);
    k_gemm1<<<800, 256, 0, stream>>>(feat, WT, H);
    k_attn1<<<2048, 256, 0, stream>>>(H, (const unsigned*)Mw, ah, bng, bnb, bnm, bnv);
    k_gemm2<<<800, 256, 0, stream>>>(H, W_sent, W_para, W_qt, Y);
    k_attn2<<<512, 512, 0, stream>>>(Y, adj, a_sent, a_para, a_qt, W2, out);
}

// Round 5
// 587.103 us; speedup vs baseline: 1.0380x; 1.0380x over previous
//
#include <hip/hip_runtime.h>
#include <hip/hip_bf16.h>

#define ALPHA   0.3f
#define NEG_INF (-9e15f)
#define BN_EPS  1e-5f

typedef _Float16 f16x4 __attribute__((ext_vector_type(4)));
typedef _Float16 f16x8 __attribute__((ext_vector_type(8)));
typedef float    f32x4 __attribute__((ext_vector_type(4)));
typedef unsigned u32x4 __attribute__((ext_vector_type(4)));
typedef unsigned long long u64;

// ---------------------------------------------------------------------------
// H layout (R9): HEAD-MAJOR. Hhm[head][51200][32] f32.
// R8 post-mortem: attn1 runs at a fixed ~3.5 TB/s and duration = bytes; the
// observed bytes were 3-5x ideal because each (b,head) block touched only a
// 128B sector of every 1KB H row (8 blocks per row, different XCDs/times ->
// partial-line amplification on both fetch and writeback). Head-major gives
// each block a CONTIGUOUS 25.6KB region: full-line streaming reads + writes,
// no cross-block line sharing. gemm1/gemm2 pay only an address change.
// ---------------------------------------------------------------------------

// ---------------------------------------------------------------------------
// K0: blocks < 768 pack Wh[8,768,32] f32 -> WcatT[256][768] f16 (B^T layout).
// All 12800 blocks pack adj>0 bitmasks Mw[row][4] u64 (41MB -> 1.6MB,
// L2-resident; aliases Y region, live only until k_attn1).
// ---------------------------------------------------------------------------
__global__ __launch_bounds__(256) void k_pack(const int* __restrict__ adj,
                                              u64* __restrict__ Mw,
                                              const float* __restrict__ Wh,
                                              _Float16* __restrict__ WT)
{
    if (blockIdx.x < 768) {
        const int o = blockIdx.x * 256 + threadIdx.x;   // < 196608
        const int n = o / 768, k = o - n * 768;
        WT[o] = (_Float16)Wh[((n >> 5) * 768 + k) * 32 + (n & 31)];
    }
    const int w = threadIdx.x >> 6, lane = threadIdx.x & 63;
    const int row = blockIdx.x * 4 + w;             // < 51200
    const int* ar = adj + (size_t)row * 200;
    #pragma unroll
    for (int t = 0; t < 4; ++t) {
        const int j = t * 64 + lane;
        const int a = ar[j < 200 ? j : 199];
        const u64 bal = __ballot(j < 200 && a > 0);
        if (lane == 0) Mw[(size_t)row * 4 + t] = bal;
    }
}

// ---------------------------------------------------------------------------
// K1: H[head-major] = feat @ Wcat via f16 MFMA.
// Tile 64Mx256N, BK=64, 4 waves. R9: epilogue writes head-major addresses
// (per 16-lane group still 64B contiguous).
// ---------------------------------------------------------------------------
__global__ __launch_bounds__(256) void k_gemm1(const float* __restrict__ A,
                                               const _Float16* __restrict__ WT,
                                               float* __restrict__ H)
{
    __shared__ _Float16 Af[64][72];    // [m][k]
    __shared__ _Float16 Bf[256][72];   // [n][k]
    const int tid  = threadIdx.x;
    const int wv   = tid >> 6;
    const int lane = tid & 63;
    const int r16  = lane & 15, q = lane >> 4;
    const size_t m_blk = (size_t)blockIdx.x * 64;
    const int wn = wv * 64;
    const int arow = tid >> 2, akb = (tid & 3) * 16;
    f32x4 acc[4][4] = {};   // [mi][ni]

    for (int kt = 0; kt < 768; kt += 64) {
        __syncthreads();
        #pragma unroll
        for (int p = 0; p < 4; ++p) {   // A: 64 rows x 64 k, f32 -> f16
            const float4 a4 = *(const float4*)&A[(m_blk + arow) * 768 + kt + akb + p * 4];
            f16x4 h4 = { (_Float16)a4.x, (_Float16)a4.y, (_Float16)a4.z, (_Float16)a4.w };
            *(f16x4*)&Af[arow][akb + p * 4] = h4;
        }
        #pragma unroll
        for (int p = 0; p < 8; ++p) {   // B: row n = tid, k 0..63 (f16 in global)
            f16x8 w8 = *(const f16x8*)&WT[tid * 768 + kt + p * 8];
            *(f16x8*)&Bf[tid][p * 8] = w8;
        }
        __syncthreads();
        #pragma unroll
        for (int kc = 0; kc < 64; kc += 32) {
            f16x8 af[4], bf[4];
            #pragma unroll
            for (int i = 0; i < 4; ++i)
                af[i] = *(const f16x8*)&Af[i * 16 + r16][kc + q * 8];
            #pragma unroll
            for (int j = 0; j < 4; ++j)
                bf[j] = *(const f16x8*)&Bf[wn + j * 16 + r16][kc + q * 8];
            #pragma unroll
            for (int i = 0; i < 4; ++i)
                #pragma unroll
                for (int j = 0; j < 4; ++j)
                    acc[i][j] = __builtin_amdgcn_mfma_f32_16x16x32_f16(
                        af[i], bf[j], acc[i][j], 0, 0, 0);
        }
    }
    #pragma unroll
    for (int i = 0; i < 4; ++i)
        #pragma unroll
        for (int j = 0; j < 4; ++j)
            #pragma unroll
            for (int r = 0; r < 4; ++r) {
                const int m = i * 16 + q * 4 + r;       // D row
                const int n = wn + j * 16 + r16;        // D col (global feature)
                // head-major: [n>>5][m_blk+m][n&31]
                H[((size_t)(n >> 5) * 51200 + m_blk + m) * 32 + (n & 31)] = acc[i][j][r];
            }
}

// ---------------------------------------------------------------------------
// K2 (R9): per (b, head) masked softmax + att@H + elu + BN, head-major H.
// Block reads its contiguous 25.6KB H slice ONCE (fused stage+score: f16 HsT
// B^T + s1/s2 via 8-lane shfl dot, f32 math -- R3 lesson), writes it back
// contiguously. Main loop = proven R6 structure: wave owns 16-row m-tile, P
// in MFMA A-fragment registers, masked max, HsT stride 232 (conflict-free
// b128), 13 tiles / 4 waves. Masks from L2-resident bitmasks.
// ---------------------------------------------------------------------------
__global__ __launch_bounds__(256, 6) void k_attn1(float* __restrict__ H,
    const unsigned* __restrict__ Mw, const float* __restrict__ ah,
    const float* __restrict__ bng, const float* __restrict__ bnb,
    const float* __restrict__ bnm, const float* __restrict__ bnv)
{
    __shared__ alignas(16) _Float16 HsT[32][232];   // [f][j] B^T, stride 464B
    __shared__ alignas(16) unsigned Ml[208][8];     // row bitmask
    __shared__ alignas(16) float s2[224];
    __shared__ alignas(16) float s1[208];
    __shared__ float bnA[208], bnB[208];
    const int tid  = threadIdx.x;
    const int b    = blockIdx.x >> 3;
    const int head = blockIdx.x & 7;
    float* Hb = H + ((size_t)head * 51200 + b * 200) * 32;   // contiguous 25.6KB
    const unsigned* Mb = Mw + (size_t)b * 200 * 8;

    // ---- fused stage + s1/s2: ONE contiguous pass over f32 H slice ----
    const int fq = tid & 7;          // lane's f-quad (f = fq*4 .. fq*4+3)
    const int gn = tid >> 3;         // row (32 rows per iteration)
    const float4 a1 = *(const float4*)&ah[head * 64 + fq * 4];
    const float4 a2 = *(const float4*)&ah[head * 64 + 32 + fq * 4];
    #pragma unroll
    for (int it = 0; it < 7; ++it) {
        const int n = gn + 32 * it;
        if (n < 200) {
            const float4 h4 = *(const float4*)&Hb[n * 32 + fq * 4];
            HsT[fq * 4 + 0][n] = (_Float16)h4.x;
            HsT[fq * 4 + 1][n] = (_Float16)h4.y;
            HsT[fq * 4 + 2][n] = (_Float16)h4.z;
            HsT[fq * 4 + 3][n] = (_Float16)h4.w;
            float v1 = h4.x * a1.x + h4.y * a1.y + h4.z * a1.z + h4.w * a1.w;
            float v2 = h4.x * a2.x + h4.y * a2.y + h4.z * a2.z + h4.w * a2.w;
            v1 += __shfl_xor(v1, 1); v2 += __shfl_xor(v2, 1);
            v1 += __shfl_xor(v1, 2); v2 += __shfl_xor(v2, 2);
            v1 += __shfl_xor(v1, 4); v2 += __shfl_xor(v2, 4);
            if (fq == 0) { s1[n] = v1; s2[n] = v2; }
        }
    }
    // K-pads of HsT (cols 200..231)
    for (int idx = tid; idx < 32 * 32; idx += 256) {
        int f = idx >> 5, c = 200 + (idx & 31);
        HsT[f][c] = (_Float16)0.f;
    }
    // masks as uint4 (208 rows x 2 uint4)
    for (int idx = tid; idx < 416; idx += 256) {
        const int rr = idx >> 1, hf = idx & 1;
        u32x4 mv = {0u, 0u, 0u, 0u};
        if (rr < 200) mv = *(const u32x4*)&Mb[rr * 8 + hf * 4];
        *(u32x4*)&Ml[rr][hf * 4] = mv;
    }
    // s1/s2 pads + fused BN coeffs
    if (tid < 8) s1[200 + tid] = 0.f;
    if (tid >= 8 && tid < 32) s2[200 + (tid - 8)] = 0.f;
    if (tid < 200) {
        const float iv = bng[tid] * rsqrtf(bnv[tid] + BN_EPS);
        bnA[tid] = iv; bnB[tid] = bnb[tid] - bnm[tid] * iv;
    }
    __syncthreads();

    const int lane = tid & 63, wv = tid >> 6;      // wv 0..3
    const int r16 = lane & 15, q = lane >> 4;

    for (int tile = wv; tile < 13; tile += 4) {
        const int m0  = tile * 16;
        const int row = m0 + r16;                  // this lane's P-row
        const float s1i = s1[row];
        const u32x4 mwa = *(const u32x4*)&Ml[row][0];
        const u32x4 mwb = *(const u32x4*)&Ml[row][4];
        const unsigned mw[7] = {mwa[0], mwa[1], mwa[2], mwa[3],
                                mwb[0], mwb[1], mwb[2]};

        // pass 1: masked row max
        float m = -INFINITY;
        #pragma unroll
        for (int ks = 0; ks < 7; ++ks) {
            const f32x4 sA = *(const f32x4*)&s2[ks * 32 + q * 8];
            const f32x4 sB = *(const f32x4*)&s2[ks * 32 + q * 8 + 4];
            const unsigned wb = mw[ks] >> (q * 8);
            #pragma unroll
            for (int e = 0; e < 8; ++e) {
                const float sv = (e < 4) ? sA[e] : sB[e - 4];
                const float t = s1i + sv;
                const float tl = fmaxf(t, ALPHA * t);   // leaky via max (a<1)
                m = fmaxf(m, ((wb >> e) & 1u) ? tl : -INFINITY);
            }
        }
        m = fmaxf(m, __shfl_xor(m, 16));
        m = fmaxf(m, __shfl_xor(m, 32));

        // pass 2: p = mask ? exp(e-m) : 0, packed straight into A-fragments
        float s = 0.f;
        f16x8 pa[7];
        #pragma unroll
        for (int ks = 0; ks < 7; ++ks) {
            const f32x4 sA = *(const f32x4*)&s2[ks * 32 + q * 8];
            const f32x4 sB = *(const f32x4*)&s2[ks * 32 + q * 8 + 4];
            const unsigned wb = mw[ks] >> (q * 8);
            #pragma unroll
            for (int e = 0; e < 8; ++e) {
                const float sv = (e < 4) ? sA[e] : sB[e - 4];
                float t = s1i + sv;
                t = fmaxf(t, ALPHA * t);
                float pe = __expf(t - m);            // <= 1: f16-safe
                pe = ((wb >> e) & 1u) ? pe : 0.f;
                s += pe;
                pa[ks][e] = (_Float16)pe;
            }
        }
        s += __shfl_xor(s, 16);
        s += __shfl_xor(s, 32);
        const float sinv = 1.f / s;

        // O[16,32] = P @ H : 2 f-tiles, A from registers, B from padded HsT
        f32x4 acc0 = {0.f, 0.f, 0.f, 0.f}, acc1 = {0.f, 0.f, 0.f, 0.f};
        #pragma unroll
        for (int ks = 0; ks < 7; ++ks) {
            const int k0 = ks * 32 + q * 8;
            const f16x8 b0 = *(const f16x8*)&HsT[r16][k0];
            const f16x8 b1 = *(const f16x8*)&HsT[16 + r16][k0];
            acc0 = __builtin_amdgcn_mfma_f32_16x16x32_f16(pa[ks], b0, acc0, 0, 0, 0);
            acc1 = __builtin_amdgcn_mfma_f32_16x16x32_f16(pa[ks], b1, acc1, 0, 0, 0);
        }
        // D layout: row = q*4+r, col = r16. sinv for row i lives at lane i&15.
        float rv[4];
        #pragma unroll
        for (int r = 0; r < 4; ++r) rv[r] = __shfl(sinv, q * 4 + r);
        #pragma unroll
        for (int r = 0; r < 4; ++r) {
            const int i = m0 + q * 4 + r;
            if (i < 200) {
                float o0 = acc0[r] * rv[r];
                float o1 = acc1[r] * rv[r];
                o0 = o0 > 0.f ? o0 : expm1f(o0);     // elu
                o1 = o1 > 0.f ? o1 : expm1f(o1);
                const float ga = bnA[i], gb = bnB[i];
                Hb[i * 32 + r16]      = o0 * ga + gb;   // contiguous 128B/row
                Hb[i * 32 + 16 + r16] = o1 * ga + gb;
            }
        }
    }
}

// ---------------------------------------------------------------------------
// K3: Y[51200,36] = x @ [W_sent | W_para | W_qt], x read from head-major H.
// Col group g (9 cols) in 16B-aligned 12-float LDS slot; unroll-4 inner loop
// (stops LLVM full-unroll spill pathology from round 1).
// ---------------------------------------------------------------------------
__global__ __launch_bounds__(256) void k_gemm2(const float* __restrict__ X,
    const float* __restrict__ Ws, const float* __restrict__ Wp,
    const float* __restrict__ Wq, float* __restrict__ Y)
{
    __shared__ float Wl[256][48];   // [k][12*g + c], c<9 used, pads never read
    __shared__ float XsT[64][68];   // [k][row]
    const int tid = threadIdx.x;
    {   // stage weights (once): thread tid = row k
        const int k = tid;
        #pragma unroll
        for (int c = 0; c < 36; ++c) {
            float v;
            if      (c == 0) v = Ws[k * 2 + 0];
            else if (c == 1) v = Ws[k * 2 + 1];
            else if (c == 2) v = Wp[k * 2 + 0];
            else if (c == 3) v = Wp[k * 2 + 1];
            else             v = Wq[k * 32 + (c - 4)];
            Wl[k][12 * (c / 9) + (c % 9)] = v;
        }
    }
    const int r  = tid & 63;        // row within tile (wave-contiguous)
    const int cg = tid >> 6;        // col group 0..3 (uniform per wave)
    const size_t row0 = (size_t)blockIdx.x * 64;
    float acc[9] = {};

    for (int kt = 0; kt < 256; kt += 64) {
        __syncthreads();
        #pragma unroll
        for (int i = 0; i < 4; ++i) {      // 64x64 X tile, transposed into LDS
            int l = tid + 256 * i;
            int row = l >> 4;
            int k4 = (l & 15) * 4;
            const int col = kt + k4;       // head-major: [col>>5][row][col&31]
            const float4 x4 = *(const float4*)&X[((size_t)(col >> 5) * 51200 + row0 + row) * 32 + (col & 31)];
            XsT[k4 + 0][row] = x4.x; XsT[k4 + 1][row] = x4.y;
            XsT[k4 + 2][row] = x4.z; XsT[k4 + 3][row] = x4.w;
        }
        __syncthreads();
        #pragma unroll 4
        for (int k = 0; k < 64; ++k) {
            const float xv = XsT[k][r];
            const float4 w0 = *(const float4*)&Wl[kt + k][12 * cg + 0];
            const float4 w1 = *(const float4*)&Wl[kt + k][12 * cg + 4];
            const float  w2 = Wl[kt + k][12 * cg + 8];
            acc[0] += xv * w0.x; acc[1] += xv * w0.y;
            acc[2] += xv * w0.z; acc[3] += xv * w0.w;
            acc[4] += xv * w1.x; acc[5] += xv * w1.y;
            acc[6] += xv * w1.z; acc[7] += xv * w1.w;
            acc[8] += xv * w2;
        }
    }
    float* yr = Y + (row0 + r) * 36 + cg * 9;
    #pragma unroll
    for (int c = 0; c < 9; ++c) yr[c] = acc[c];
}

// ---------------------------------------------------------------------------
// K4: 2nd-layer attention, 512 threads (R7 version: stage 14 iters, 8-wave
// row loop). Direct adj loads (Mw is dead -- overwritten by k_gemm2).
// ---------------------------------------------------------------------------
__global__ __launch_bounds__(512, 4) void k_attn2(const float* __restrict__ Y,
    const int* __restrict__ adj, const float* __restrict__ a_s,
    const float* __restrict__ a_p, const float* __restrict__ a_q,
    const float* __restrict__ W2, float* __restrict__ out)
{
    __shared__ float Ys[200][37];
    __shared__ float s1s[200], s2s[200], p1s[200], p2s[200], sq2[200];
    __shared__ float p0[200];
    __shared__ float hqt[32];
    __shared__ float sumq_s;
    __shared__ float asl[4], apl[4], aql[64], w2l[64];
    const int tid  = threadIdx.x;
    const int b    = blockIdx.x >> 1;
    const int half = blockIdx.x & 1;
    const float* Yb = Y + (size_t)b * 7200;
    const int* adjb = adj + (size_t)b * 200 * 200;

    for (int idx = tid; idx < 7200; idx += 512) {
        int j = idx / 36;
        int c = idx - j * 36;
        Ys[j][c] = Yb[idx];
    }
    if (tid < 4)  { asl[tid] = a_s[tid]; apl[tid] = a_p[tid]; }
    if (tid >= 64 && tid < 128) { aql[tid - 64] = a_q[tid - 64]; w2l[tid - 64] = W2[tid - 64]; }
    __syncthreads();

    if (tid < 200) {
        int j = tid;
        s1s[j] = Ys[j][0] * asl[0] + Ys[j][1] * asl[1];
        s2s[j] = Ys[j][0] * asl[2] + Ys[j][1] * asl[3];
        p1s[j] = Ys[j][2] * apl[0] + Ys[j][3] * apl[1];
        p2s[j] = Ys[j][2] * apl[2] + Ys[j][3] * apl[3];
        float a = 0.f;
        #pragma unroll
        for (int f = 0; f < 32; ++f) a += Ys[j][4 + f] * aql[32 + f];
        sq2[j] = a;
    }
    __syncthreads();

    const int w = tid >> 6, lane = tid & 63;       // w 0..7
    for (int ii = w; ii < 100; ii += 8) {   // one wave per row
        const int i = half * 100 + ii;
        const float s1i = s1s[i], p1i = p1s[i];
        float ms = -INFINITY, mp = -INFINITY;
        float es[4], ep[4];
        #pragma unroll
        for (int t = 0; t < 4; ++t) {
            int j = lane + 64 * t;
            int jj = j < 200 ? j : 0;
            int a = (j < 200) ? adjb[i * 200 + j] : 0;
            float e1 = s1i + s2s[jj]; e1 = e1 >= 0.f ? e1 : ALPHA * e1;
            float e2 = p1i + p2s[jj]; e2 = e2 >= 0.f ? e2 : ALPHA * e2;
            es[t] = (a > 0) ? e1 : (j < 200 ? NEG_INF : -INFINITY);
            ep[t] = (a > 0) ? e2 : (j < 200 ? NEG_INF : -INFINITY);
            ms = fmaxf(ms, es[t]); mp = fmaxf(mp, ep[t]);
        }
        #pragma unroll
        for (int off = 32; off >= 1; off >>= 1) {
            ms = fmaxf(ms, __shfl_xor(ms, off));
            mp = fmaxf(mp, __shfl_xor(mp, off));
        }
        float ss = 0.f, sp = 0.f, os0 = 0.f, os1 = 0.f, op0 = 0.f, op1 = 0.f;
        #pragma unroll
        for (int t = 0; t < 4; ++t) {
            int j = lane + 64 * t;
            int jj = j < 200 ? j : 0;
            float pes = __expf(es[t] - ms);
            float pep = __expf(ep[t] - mp);
            ss += pes; sp += pep;
            os0 += pes * Ys[jj][0]; os1 += pes * Ys[jj][1];
            op0 += pep * Ys[jj][2]; op1 += pep * Ys[jj][3];
        }
        #pragma unroll
        for (int off = 32; off >= 1; off >>= 1) {
            ss  += __shfl_xor(ss, off);  sp  += __shfl_xor(sp, off);
            os0 += __shfl_xor(os0, off); os1 += __shfl_xor(os1, off);
            op0 += __shfl_xor(op0, off); op1 += __shfl_xor(op1, off);
        }
        if (lane == 0) {
            float v0 = os0 / ss, v1 = os1 / ss;
            out[((size_t)b * 200 + i) * 2 + 0] = 1.f / (1.f + __expf(-v0));
            out[((size_t)b * 200 + i) * 2 + 1] = 1.f / (1.f + __expf(-v1));
            float q0 = op0 / sp, q1 = op1 / sp;
            out[102400 + ((size_t)b * 200 + i) * 2 + 0] = q0 > 0.f ? q0 : expm1f(q0);
            out[102400 + ((size_t)b * 200 + i) * 2 + 1] = q1 > 0.f ? q1 : expm1f(q1);
        }
    }

    // ---- qtype head: attention row 0 only (half 0 blocks) ----
    if (half == 0 && tid < 64) {
        float s1q = 0.f;
        #pragma unroll
        for (int f = 0; f < 32; ++f) s1q += Ys[0][4 + f] * aql[f];
        float mq = -INFINITY;
        float eq[4];
        #pragma unroll
        for (int t = 0; t < 4; ++t) {
            int j = tid + 64 * t;
            int jj = j < 200 ? j : 0;
            int a = (j < 200) ? adjb[j] : 0;
            float e = s1q + sq2[jj]; e = e >= 0.f ? e : ALPHA * e;
            eq[t] = (a > 0) ? e : (j < 200 ? NEG_INF : -INFINITY);
            mq = fmaxf(mq, eq[t]);
        }
        #pragma unroll
        for (int off = 32; off >= 1; off >>= 1) mq = fmaxf(mq, __shfl_xor(mq, off));
        float sq = 0.f;
        #pragma unroll
        for (int t = 0; t < 4; ++t) {
            int j = tid + 64 * t;
            float pe = __expf(eq[t] - mq);
            sq += pe;
            if (j < 200) p0[j] = pe;
        }
        #pragma unroll
        for (int off = 32; off >= 1; off >>= 1) sq += __shfl_xor(sq, off);
        if (tid == 0) sumq_s = sq;
    }
    __syncthreads();
    if (half == 0 && tid < 32) {
        float acc = 0.f;
        for (int j = 0; j < 200; ++j) acc += p0[j] * Ys[j][4 + tid];
        hqt[tid] = acc / sumq_s;
    }
    __syncthreads();
    if (half == 0 && tid < 2) {
        float v = 0.f;
        #pragma unroll
        for (int f = 0; f < 32; ++f) v += hqt[f] * w2l[f * 2 + tid];
        out[204800 + (size_t)b * 2 + tid] = v > 0.f ? v : expm1f(v);
    }
}

// ---------------------------------------------------------------------------
extern "C" void kernel_launch(void* const* d_in, const int* in_sizes, int n_in,
                              void* d_out, int out_size, void* d_ws, size_t ws_size,
                              hipStream_t stream) {
    const float* feat   = (const float*)d_in[0];   // [256,200,768]
    const int*   adj    = (const int*)  d_in[1];   // [256,200,200]
    const float* Wh     = (const float*)d_in[2];   // [8,768,32]
    const float* ah     = (const float*)d_in[3];   // [8,64,1]
    const float* W_sent = (const float*)d_in[4];   // [256,2]
    const float* a_sent = (const float*)d_in[5];   // [4,1]
    const float* W_para = (const float*)d_in[6];   // [256,2]
    const float* a_para = (const float*)d_in[7];   // [4,1]
    const float* W_qt   = (const float*)d_in[8];   // [256,32]
    const float* a_qt   = (const float*)d_in[9];   // [64,1]
    const float* W2     = (const float*)d_in[10];  // [32,2]
    const float* bng    = (const float*)d_in[11];
    const float* bnb    = (const float*)d_in[12];
    const float* bnm    = (const float*)d_in[13];
    const float* bnv    = (const float*)d_in[14];

    float* H = (float*)d_ws;                 // head-major [8][51200][32] f32
    float* Y = H + (size_t)51200 * 256;      // [51200,36]
    _Float16* WT = (_Float16*)(Y + (size_t)51200 * 36);  // [256,768] f16
    // Mw [51200][4] u64 = 1.6MB ALIASES Y (live only between k_pack and
    // k_attn1; k_gemm2 overwrites it afterwards). Footprint unchanged.
    u64* Mw = (u64*)Y;
    float* out = (float*)d_out;

    k_pack<<<12800, 256, 0, stream>>>(adj, Mw, Wh, WT);
    k_gemm1<<<800, 256, 0, stream>>>(feat, WT, H);
    k_attn1<<<2048, 256, 0, stream>>>(H, (const unsigned*)Mw, ah, bng, bnb, bnm, bnv);
    k_gemm2<<<800, 256, 0, stream>>>(H, W_sent, W_para, W_qt, Y);
    k_attn2<<<512, 512, 0, stream>>>(Y, adj, a_sent, a_para, a_qt, W2, out);
}

// Round 6
// 522.702 us; speedup vs baseline: 1.1658x; 1.1232x over previous
//
#include <hip/hip_runtime.h>
#include <hip/hip_bf16.h>

#define ALPHA   0.3f
#define NEG_INF (-9e15f)
#define BN_EPS  1e-5f

typedef _Float16 f16x4 __attribute__((ext_vector_type(4)));
typedef _Float16 f16x8 __attribute__((ext_vector_type(8)));
typedef float    f32x4 __attribute__((ext_vector_type(4)));
typedef unsigned u32x4 __attribute__((ext_vector_type(4)));
typedef unsigned long long u64;

// ---------------------------------------------------------------------------
// R10 theory: R6-R9 attn1 all moved ~700MB at ~3.6 TB/s regardless of global
// access geometry (R9's fully-contiguous head-major changed NOTHING: 417/291
// MB). Geometry-invariant, thread-proportional excess ==> REGISTER SPILLS.
// VGPR_Count=40 vs ~70+ live (pa[7]=28, mw[7]=7, acc=8, temps) -> pa spilled
// to scratch, reloaded in MFMA phase: 2048*256*~600B round-trips ~ 350MB HBM.
// Fix: fuse pass2 with MFMA (one pa fragment live at a time; acc carries the
// K-sum) + launch_bounds(256,4) (VGPR cap 128). Arithmetic order unchanged.
// ---------------------------------------------------------------------------

// ---------------------------------------------------------------------------
// K0: blocks < 768 pack Wh[8,768,32] f32 -> WcatT[256][768] f16 (B^T layout).
// All 12800 blocks pack adj>0 bitmasks Mw[row][4] u64 (41MB -> 1.6MB,
// L2-resident; aliases Y region, live only until k_attn1).
// ---------------------------------------------------------------------------
__global__ __launch_bounds__(256) void k_pack(const int* __restrict__ adj,
                                              u64* __restrict__ Mw,
                                              const float* __restrict__ Wh,
                                              _Float16* __restrict__ WT)
{
    if (blockIdx.x < 768) {
        const int o = blockIdx.x * 256 + threadIdx.x;   // < 196608
        const int n = o / 768, k = o - n * 768;
        WT[o] = (_Float16)Wh[((n >> 5) * 768 + k) * 32 + (n & 31)];
    }
    const int w = threadIdx.x >> 6, lane = threadIdx.x & 63;
    const int row = blockIdx.x * 4 + w;             // < 51200
    const int* ar = adj + (size_t)row * 200;
    #pragma unroll
    for (int t = 0; t < 4; ++t) {
        const int j = t * 64 + lane;
        const int a = ar[j < 200 ? j : 199];
        const u64 bal = __ballot(j < 200 && a > 0);
        if (lane == 0) Mw[(size_t)row * 4 + t] = bal;
    }
}

// ---------------------------------------------------------------------------
// K1: H[head-major [8][51200][32]] = feat @ Wcat via f16 MFMA.
// Tile 64Mx256N, BK=64, 4 waves. Epilogue writes head-major (64B contiguous
// per 16-lane group).
// ---------------------------------------------------------------------------
__global__ __launch_bounds__(256) void k_gemm1(const float* __restrict__ A,
                                               const _Float16* __restrict__ WT,
                                               float* __restrict__ H)
{
    __shared__ _Float16 Af[64][72];    // [m][k]
    __shared__ _Float16 Bf[256][72];   // [n][k]
    const int tid  = threadIdx.x;
    const int wv   = tid >> 6;
    const int lane = tid & 63;
    const int r16  = lane & 15, q = lane >> 4;
    const size_t m_blk = (size_t)blockIdx.x * 64;
    const int wn = wv * 64;
    const int arow = tid >> 2, akb = (tid & 3) * 16;
    f32x4 acc[4][4] = {};   // [mi][ni]

    for (int kt = 0; kt < 768; kt += 64) {
        __syncthreads();
        #pragma unroll
        for (int p = 0; p < 4; ++p) {   // A: 64 rows x 64 k, f32 -> f16
            const float4 a4 = *(const float4*)&A[(m_blk + arow) * 768 + kt + akb + p * 4];
            f16x4 h4 = { (_Float16)a4.x, (_Float16)a4.y, (_Float16)a4.z, (_Float16)a4.w };
            *(f16x4*)&Af[arow][akb + p * 4] = h4;
        }
        #pragma unroll
        for (int p = 0; p < 8; ++p) {   // B: row n = tid, k 0..63 (f16 in global)
            f16x8 w8 = *(const f16x8*)&WT[tid * 768 + kt + p * 8];
            *(f16x8*)&Bf[tid][p * 8] = w8;
        }
        __syncthreads();
        #pragma unroll
        for (int kc = 0; kc < 64; kc += 32) {
            f16x8 af[4], bf[4];
            #pragma unroll
            for (int i = 0; i < 4; ++i)
                af[i] = *(const f16x8*)&Af[i * 16 + r16][kc + q * 8];
            #pragma unroll
            for (int j = 0; j < 4; ++j)
                bf[j] = *(const f16x8*)&Bf[wn + j * 16 + r16][kc + q * 8];
            #pragma unroll
            for (int i = 0; i < 4; ++i)
                #pragma unroll
                for (int j = 0; j < 4; ++j)
                    acc[i][j] = __builtin_amdgcn_mfma_f32_16x16x32_f16(
                        af[i], bf[j], acc[i][j], 0, 0, 0);
        }
    }
    #pragma unroll
    for (int i = 0; i < 4; ++i)
        #pragma unroll
        for (int j = 0; j < 4; ++j)
            #pragma unroll
            for (int r = 0; r < 4; ++r) {
                const int m = i * 16 + q * 4 + r;       // D row
                const int n = wn + j * 16 + r16;        // D col (global feature)
                H[((size_t)(n >> 5) * 51200 + m_blk + m) * 32 + (n & 31)] = acc[i][j][r];
            }
}

// ---------------------------------------------------------------------------
// K2 (R10): per (b, head) masked softmax + att@H + elu + BN, head-major H.
// Fused stage+score single pass over the contiguous 25.6KB slice (f16 HsT B^T
// + s1/s2 via 8-lane shfl dot, f32 math -- R3 lesson). Tile loop: pass1 =
// masked max; pass2 FUSED with MFMA -- per k-slice: 8 exps -> one f16x8
// fragment -> 2 MFMAs immediately (acc carries K-sum). Only ~45 live VGPRs:
// no spill (R10 fix; R6-R9 spilled pa[7] -> ~350MB scratch HBM traffic).
// HsT stride 232 = conflict-free b128. Masks from L2-resident bitmasks.
// ---------------------------------------------------------------------------
__global__ __launch_bounds__(256, 4) void k_attn1(float* __restrict__ H,
    const unsigned* __restrict__ Mw, const float* __restrict__ ah,
    const float* __restrict__ bng, const float* __restrict__ bnb,
    const float* __restrict__ bnm, const float* __restrict__ bnv)
{
    __shared__ alignas(16) _Float16 HsT[32][232];   // [f][j] B^T, stride 464B
    __shared__ alignas(16) unsigned Ml[208][8];     // row bitmask
    __shared__ alignas(16) float s2[224];
    __shared__ alignas(16) float s1[208];
    __shared__ float bnA[208], bnB[208];
    const int tid  = threadIdx.x;
    const int b    = blockIdx.x >> 3;
    const int head = blockIdx.x & 7;
    float* Hb = H + ((size_t)head * 51200 + b * 200) * 32;   // contiguous 25.6KB
    const unsigned* Mb = Mw + (size_t)b * 200 * 8;

    // ---- fused stage + s1/s2: ONE contiguous pass over f32 H slice ----
    const int fq = tid & 7;          // lane's f-quad (f = fq*4 .. fq*4+3)
    const int gn = tid >> 3;         // row (32 rows per iteration)
    const float4 a1 = *(const float4*)&ah[head * 64 + fq * 4];
    const float4 a2 = *(const float4*)&ah[head * 64 + 32 + fq * 4];
    #pragma unroll
    for (int it = 0; it < 7; ++it) {
        const int n = gn + 32 * it;
        if (n < 200) {
            const float4 h4 = *(const float4*)&Hb[n * 32 + fq * 4];
            HsT[fq * 4 + 0][n] = (_Float16)h4.x;
            HsT[fq * 4 + 1][n] = (_Float16)h4.y;
            HsT[fq * 4 + 2][n] = (_Float16)h4.z;
            HsT[fq * 4 + 3][n] = (_Float16)h4.w;
            float v1 = h4.x * a1.x + h4.y * a1.y + h4.z * a1.z + h4.w * a1.w;
            float v2 = h4.x * a2.x + h4.y * a2.y + h4.z * a2.z + h4.w * a2.w;
            v1 += __shfl_xor(v1, 1); v2 += __shfl_xor(v2, 1);
            v1 += __shfl_xor(v1, 2); v2 += __shfl_xor(v2, 2);
            v1 += __shfl_xor(v1, 4); v2 += __shfl_xor(v2, 4);
            if (fq == 0) { s1[n] = v1; s2[n] = v2; }
        }
    }
    // K-pads of HsT (cols 200..231)
    for (int idx = tid; idx < 32 * 32; idx += 256) {
        int f = idx >> 5, c = 200 + (idx & 31);
        HsT[f][c] = (_Float16)0.f;
    }
    // masks as uint4 (208 rows x 2 uint4)
    for (int idx = tid; idx < 416; idx += 256) {
        const int rr = idx >> 1, hf = idx & 1;
        u32x4 mv = {0u, 0u, 0u, 0u};
        if (rr < 200) mv = *(const u32x4*)&Mb[rr * 8 + hf * 4];
        *(u32x4*)&Ml[rr][hf * 4] = mv;
    }
    // s1/s2 pads + fused BN coeffs
    if (tid < 8) s1[200 + tid] = 0.f;
    if (tid >= 8 && tid < 32) s2[200 + (tid - 8)] = 0.f;
    if (tid < 200) {
        const float iv = bng[tid] * rsqrtf(bnv[tid] + BN_EPS);
        bnA[tid] = iv; bnB[tid] = bnb[tid] - bnm[tid] * iv;
    }
    __syncthreads();

    const int lane = tid & 63, wv = tid >> 6;      // wv 0..3
    const int r16 = lane & 15, q = lane >> 4;

    for (int tile = wv; tile < 13; tile += 4) {
        const int m0  = tile * 16;
        const int row = m0 + r16;                  // this lane's P-row
        const float s1i = s1[row];
        const u32x4 mwa = *(const u32x4*)&Ml[row][0];
        const u32x4 mwb = *(const u32x4*)&Ml[row][4];
        const unsigned mw[7] = {mwa[0], mwa[1], mwa[2], mwa[3],
                                mwb[0], mwb[1], mwb[2]};

        // pass 1: masked row max
        float m = -INFINITY;
        #pragma unroll
        for (int ks = 0; ks < 7; ++ks) {
            const f32x4 sA = *(const f32x4*)&s2[ks * 32 + q * 8];
            const f32x4 sB = *(const f32x4*)&s2[ks * 32 + q * 8 + 4];
            const unsigned wb = mw[ks] >> (q * 8);
            #pragma unroll
            for (int e = 0; e < 8; ++e) {
                const float sv = (e < 4) ? sA[e] : sB[e - 4];
                const float t = s1i + sv;
                const float tl = fmaxf(t, ALPHA * t);   // leaky via max (a<1)
                m = fmaxf(m, ((wb >> e) & 1u) ? tl : -INFINITY);
            }
        }
        m = fmaxf(m, __shfl_xor(m, 16));
        m = fmaxf(m, __shfl_xor(m, 32));

        // pass 2 FUSED with MFMA: one k-slice fragment live at a time.
        float s = 0.f;
        f32x4 acc0 = {0.f, 0.f, 0.f, 0.f}, acc1 = {0.f, 0.f, 0.f, 0.f};
        #pragma unroll
        for (int ks = 0; ks < 7; ++ks) {
            const f32x4 sA = *(const f32x4*)&s2[ks * 32 + q * 8];
            const f32x4 sB = *(const f32x4*)&s2[ks * 32 + q * 8 + 4];
            const unsigned wb = mw[ks] >> (q * 8);
            f16x8 pa;
            #pragma unroll
            for (int e = 0; e < 8; ++e) {
                const float sv = (e < 4) ? sA[e] : sB[e - 4];
                float t = s1i + sv;
                t = fmaxf(t, ALPHA * t);
                float pe = __expf(t - m);            // <= 1: f16-safe
                pe = ((wb >> e) & 1u) ? pe : 0.f;
                s += pe;
                pa[e] = (_Float16)pe;
            }
            const int k0 = ks * 32 + q * 8;
            const f16x8 b0 = *(const f16x8*)&HsT[r16][k0];
            const f16x8 b1 = *(const f16x8*)&HsT[16 + r16][k0];
            acc0 = __builtin_amdgcn_mfma_f32_16x16x32_f16(pa, b0, acc0, 0, 0, 0);
            acc1 = __builtin_amdgcn_mfma_f32_16x16x32_f16(pa, b1, acc1, 0, 0, 0);
        }
        s += __shfl_xor(s, 16);
        s += __shfl_xor(s, 32);
        const float sinv = 1.f / s;

        // D layout: row = q*4+r, col = r16. sinv for row i lives at lane i&15.
        float rv[4];
        #pragma unroll
        for (int r = 0; r < 4; ++r) rv[r] = __shfl(sinv, q * 4 + r);
        #pragma unroll
        for (int r = 0; r < 4; ++r) {
            const int i = m0 + q * 4 + r;
            if (i < 200) {
                float o0 = acc0[r] * rv[r];
                float o1 = acc1[r] * rv[r];
                o0 = o0 > 0.f ? o0 : expm1f(o0);     // elu
                o1 = o1 > 0.f ? o1 : expm1f(o1);
                const float ga = bnA[i], gb = bnB[i];
                Hb[i * 32 + r16]      = o0 * ga + gb;   // contiguous 128B/row
                Hb[i * 32 + 16 + r16] = o1 * ga + gb;
            }
        }
    }
}

// ---------------------------------------------------------------------------
// K3: Y[51200,36] = x @ [W_sent | W_para | W_qt], x read from head-major H.
// Col group g (9 cols) in 16B-aligned 12-float LDS slot; unroll-4 inner loop
// (stops LLVM full-unroll spill pathology from round 1).
// ---------------------------------------------------------------------------
__global__ __launch_bounds__(256) void k_gemm2(const float* __restrict__ X,
    const float* __restrict__ Ws, const float* __restrict__ Wp,
    const float* __restrict__ Wq, float* __restrict__ Y)
{
    __shared__ float Wl[256][48];   // [k][12*g + c], c<9 used, pads never read
    __shared__ float XsT[64][68];   // [k][row]
    const int tid = threadIdx.x;
    {   // stage weights (once): thread tid = row k
        const int k = tid;
        #pragma unroll
        for (int c = 0; c < 36; ++c) {
            float v;
            if      (c == 0) v = Ws[k * 2 + 0];
            else if (c == 1) v = Ws[k * 2 + 1];
            else if (c == 2) v = Wp[k * 2 + 0];
            else if (c == 3) v = Wp[k * 2 + 1];
            else             v = Wq[k * 32 + (c - 4)];
            Wl[k][12 * (c / 9) + (c % 9)] = v;
        }
    }
    const int r  = tid & 63;        // row within tile (wave-contiguous)
    const int cg = tid >> 6;        // col group 0..3 (uniform per wave)
    const size_t row0 = (size_t)blockIdx.x * 64;
    float acc[9] = {};

    for (int kt = 0; kt < 256; kt += 64) {
        __syncthreads();
        #pragma unroll
        for (int i = 0; i < 4; ++i) {      // 64x64 X tile, transposed into LDS
            int l = tid + 256 * i;
            int row = l >> 4;
            int k4 = (l & 15) * 4;
            const int col = kt + k4;       // head-major: [col>>5][row][col&31]
            const float4 x4 = *(const float4*)&X[((size_t)(col >> 5) * 51200 + row0 + row) * 32 + (col & 31)];
            XsT[k4 + 0][row] = x4.x; XsT[k4 + 1][row] = x4.y;
            XsT[k4 + 2][row] = x4.z; XsT[k4 + 3][row] = x4.w;
        }
        __syncthreads();
        #pragma unroll 4
        for (int k = 0; k < 64; ++k) {
            const float xv = XsT[k][r];
            const float4 w0 = *(const float4*)&Wl[kt + k][12 * cg + 0];
            const float4 w1 = *(const float4*)&Wl[kt + k][12 * cg + 4];
            const float  w2 = Wl[kt + k][12 * cg + 8];
            acc[0] += xv * w0.x; acc[1] += xv * w0.y;
            acc[2] += xv * w0.z; acc[3] += xv * w0.w;
            acc[4] += xv * w1.x; acc[5] += xv * w1.y;
            acc[6] += xv * w1.z; acc[7] += xv * w1.w;
            acc[8] += xv * w2;
        }
    }
    float* yr = Y + (row0 + r) * 36 + cg * 9;
    #pragma unroll
    for (int c = 0; c < 9; ++c) yr[c] = acc[c];
}

// ---------------------------------------------------------------------------
// K4: 2nd-layer attention, 512 threads (stage 14 iters, 8-wave row loop).
// Direct adj loads (Mw is dead -- overwritten by k_gemm2).
// ---------------------------------------------------------------------------
__global__ __launch_bounds__(512, 4) void k_attn2(const float* __restrict__ Y,
    const int* __restrict__ adj, const float* __restrict__ a_s,
    const float* __restrict__ a_p, const float* __restrict__ a_q,
    const float* __restrict__ W2, float* __restrict__ out)
{
    __shared__ float Ys[200][37];
    __shared__ float s1s[200], s2s[200], p1s[200], p2s[200], sq2[200];
    __shared__ float p0[200];
    __shared__ float hqt[32];
    __shared__ float sumq_s;
    __shared__ float asl[4], apl[4], aql[64], w2l[64];
    const int tid  = threadIdx.x;
    const int b    = blockIdx.x >> 1;
    const int half = blockIdx.x & 1;
    const float* Yb = Y + (size_t)b * 7200;
    const int* adjb = adj + (size_t)b * 200 * 200;

    for (int idx = tid; idx < 7200; idx += 512) {
        int j = idx / 36;
        int c = idx - j * 36;
        Ys[j][c] = Yb[idx];
    }
    if (tid < 4)  { asl[tid] = a_s[tid]; apl[tid] = a_p[tid]; }
    if (tid >= 64 && tid < 128) { aql[tid - 64] = a_q[tid - 64]; w2l[tid - 64] = W2[tid - 64]; }
    __syncthreads();

    if (tid < 200) {
        int j = tid;
        s1s[j] = Ys[j][0] * asl[0] + Ys[j][1] * asl[1];
        s2s[j] = Ys[j][0] * asl[2] + Ys[j][1] * asl[3];
        p1s[j] = Ys[j][2] * apl[0] + Ys[j][3] * apl[1];
        p2s[j] = Ys[j][2] * apl[2] + Ys[j][3] * apl[3];
        float a = 0.f;
        #pragma unroll
        for (int f = 0; f < 32; ++f) a += Ys[j][4 + f] * aql[32 + f];
        sq2[j] = a;
    }
    __syncthreads();

    const int w = tid >> 6, lane = tid & 63;       // w 0..7
    for (int ii = w; ii < 100; ii += 8) {   // one wave per row
        const int i = half * 100 + ii;
        const float s1i = s1s[i], p1i = p1s[i];
        float ms = -INFINITY, mp = -INFINITY;
        float es[4], ep[4];
        #pragma unroll
        for (int t = 0; t < 4; ++t) {
            int j = lane + 64 * t;
            int jj = j < 200 ? j : 0;
            int a = (j < 200) ? adjb[i * 200 + j] : 0;
            float e1 = s1i + s2s[jj]; e1 = e1 >= 0.f ? e1 : ALPHA * e1;
            float e2 = p1i + p2s[jj]; e2 = e2 >= 0.f ? e2 : ALPHA * e2;
            es[t] = (a > 0) ? e1 : (j < 200 ? NEG_INF : -INFINITY);
            ep[t] = (a > 0) ? e2 : (j < 200 ? NEG_INF : -INFINITY);
            ms = fmaxf(ms, es[t]); mp = fmaxf(mp, ep[t]);
        }
        #pragma unroll
        for (int off = 32; off >= 1; off >>= 1) {
            ms = fmaxf(ms, __shfl_xor(ms, off));
            mp = fmaxf(mp, __shfl_xor(mp, off));
        }
        float ss = 0.f, sp = 0.f, os0 = 0.f, os1 = 0.f, op0 = 0.f, op1 = 0.f;
        #pragma unroll
        for (int t = 0; t < 4; ++t) {
            int j = lane + 64 * t;
            int jj = j < 200 ? j : 0;
            float pes = __expf(es[t] - ms);
            float pep = __expf(ep[t] - mp);
            ss += pes; sp += pep;
            os0 += pes * Ys[jj][0]; os1 += pes * Ys[jj][1];
            op0 += pep * Ys[jj][2]; op1 += pep * Ys[jj][3];
        }
        #pragma unroll
        for (int off = 32; off >= 1; off >>= 1) {
            ss  += __shfl_xor(ss, off);  sp  += __shfl_xor(sp, off);
            os0 += __shfl_xor(os0, off); os1 += __shfl_xor(os1, off);
            op0 += __shfl_xor(op0, off); op1 += __shfl_xor(op1, off);
        }
        if (lane == 0) {
            float v0 = os0 / ss, v1 = os1 / ss;
            out[((size_t)b * 200 + i) * 2 + 0] = 1.f / (1.f + __expf(-v0));
            out[((size_t)b * 200 + i) * 2 + 1] = 1.f / (1.f + __expf(-v1));
            float q0 = op0 / sp, q1 = op1 / sp;
            out[102400 + ((size_t)b * 200 + i) * 2 + 0] = q0 > 0.f ? q0 : expm1f(q0);
            out[102400 + ((size_t)b * 200 + i) * 2 + 1] = q1 > 0.f ? q1 : expm1f(q1);
        }
    }

    // ---- qtype head: attention row 0 only (half 0 blocks) ----
    if (half == 0 && tid < 64) {
        float s1q = 0.f;
        #pragma unroll
        for (int f = 0; f < 32; ++f) s1q += Ys[0][4 + f] * aql[f];
        float mq = -INFINITY;
        float eq[4];
        #pragma unroll
        for (int t = 0; t < 4; ++t) {
            int j = tid + 64 * t;
            int jj = j < 200 ? j : 0;
            int a = (j < 200) ? adjb[j] : 0;
            float e = s1q + sq2[jj]; e = e >= 0.f ? e : ALPHA * e;
            eq[t] = (a > 0) ? e : (j < 200 ? NEG_INF : -INFINITY);
            mq = fmaxf(mq, eq[t]);
        }
        #pragma unroll
        for (int off = 32; off >= 1; off >>= 1) mq = fmaxf(mq, __shfl_xor(mq, off));
        float sq = 0.f;
        #pragma unroll
        for (int t = 0; t < 4; ++t) {
            int j = tid + 64 * t;
            float pe = __expf(eq[t] - mq);
            sq += pe;
            if (j < 200) p0[j] = pe;
        }
        #pragma unroll
        for (int off = 32; off >= 1; off >>= 1) sq += __shfl_xor(sq, off);
        if (tid == 0) sumq_s = sq;
    }
    __syncthreads();
    if (half == 0 && tid < 32) {
        float acc = 0.f;
        for (int j = 0; j < 200; ++j) acc += p0[j] * Ys[j][4 + tid];
        hqt[tid] = acc / sumq_s;
    }
    __syncthreads();
    if (half == 0 && tid < 2) {
        float v = 0.f;
        #pragma unroll
        for (int f = 0; f < 32; ++f) v += hqt[f] * w2l[f * 2 + tid];
        out[204800 + (size_t)b * 2 + tid] = v > 0.f ? v : expm1f(v);
    }
}

// ---------------------------------------------------------------------------
extern "C" void kernel_launch(void* const* d_in, const int* in_sizes, int n_in,
                              void* d_out, int out_size, void* d_ws, size_t ws_size,
                              hipStream_t stream) {
    const float* feat   = (const float*)d_in[0];   // [256,200,768]
    const int*   adj    = (const int*)  d_in[1];   // [256,200,200]
    const float* Wh     = (const float*)d_in[2];   // [8,768,32]
    const float* ah     = (const float*)d_in[3];   // [8,64,1]
    const float* W_sent = (const float*)d_in[4];   // [256,2]
    const float* a_sent = (const float*)d_in[5];   // [4,1]
    const float* W_para = (const float*)d_in[6];   // [256,2]
    const float* a_para = (const float*)d_in[7];   // [4,1]
    const float* W_qt   = (const float*)d_in[8];   // [256,32]
    const float* a_qt   = (const float*)d_in[9];   // [64,1]
    const float* W2     = (const float*)d_in[10];  // [32,2]
    const float* bng    = (const float*)d_in[11];
    const float* bnb    = (const float*)d_in[12];
    const float* bnm    = (const float*)d_in[13];
    const float* bnv    = (const float*)d_in[14];

    float* H = (float*)d_ws;                 // head-major [8][51200][32] f32
    float* Y = H + (size_t)51200 * 256;      // [51200,36]
    _Float16* WT = (_Float16*)(Y + (size_t)51200 * 36);  // [256,768] f16
    // Mw [51200][4] u64 = 1.6MB ALIASES Y (live only between k_pack and
    // k_attn1; k_gemm2 overwrites it afterwards). Footprint unchanged.
    u64* Mw = (u64*)Y;
    float* out = (float*)d_out;

    k_pack<<<12800, 256, 0, stream>>>(adj, Mw, Wh, WT);
    k_gemm1<<<800, 256, 0, stream>>>(feat, WT, H);
    k_attn1<<<2048, 256, 0, stream>>>(H, (const unsigned*)Mw, ah, bng, bnb, bnm, bnv);
    k_gemm2<<<800, 256, 0, stream>>>(H, W_sent, W_para, W_qt, Y);
    k_attn2<<<512, 512, 0, stream>>>(Y, adj, a_sent, a_para, a_qt, W2, out);
}